// Round 15
// baseline (299.711 us; speedup 1.0000x reference)
//
#include <hip/hip_runtime.h>
#include <hip/hip_bf16.h>

typedef unsigned short u16;
typedef unsigned int u32;

#define BATCH 4
#define NHIST 4
#define NPART 1000
#define NTOPK 10
#define NPT (BATCH*NPART)     // 4000 particles total
#define NET (NPT*NTOPK)       // 40000 edges capacity
#define EREG 5000             // per-region edge capacity (8 regions)
#define NRT 157               // relation tiles per region (ceil(EREG/32))

typedef __bf16 b8v __attribute__((ext_vector_type(8)));
typedef float  f4v __attribute__((ext_vector_type(4)));

__device__ __forceinline__ float bf2f(u16 b){
    return __uint_as_float(((u32)b) << 16);
}
__device__ __forceinline__ u16 f2bf(float f){
    u32 u = __float_as_uint(f);
    u32 r = u + 0x7FFF + ((u >> 16) & 1);  // RNE
    return (u16)(r >> 16);
}
__device__ __forceinline__ float ldin(const void* p, size_t i, int isf32){
    return isf32 ? ((const float*)p)[i] : bf2f(((const u16*)p)[i]);
}

// =============== setup: dtype-probe + weight swizzle + prep + topk+compact ===============
// grid 1090: blocks 0..73 weight swizzle, 74..89 prep, 90..1089 topk (wave = receiver).
// Compaction: 8 region counters (block tb -> region tb&7, base r*EREG), 1 atomic/block.
__global__ __launch_bounds__(256) void k_setup(
    const void* __restrict__ a_hist, const void* __restrict__ s_hist,
    const void* __restrict__ s_delta,
    const void* w0, const void* w1, const void* w2, const void* w3,
    const void* w4, const void* w5, const void* w6, const void* w7,
    u16* __restrict__ wsw, int* __restrict__ dflag,
    float* __restrict__ s_cur, u16* __restrict__ pe_in,
    int* __restrict__ ecount8, int* __restrict__ cidx, int* __restrict__ csend,
    u16* __restrict__ re_in)
{
    __shared__ u32 SMEM[8192];        // 32 KB, multi-purpose
    __shared__ int sdet;
    __shared__ int wcnt[4], wbase[4];
    int t = threadIdx.x;
    if (t == 0) sdet = 0;
    __syncthreads();
    {
        const u16* p = (const u16*)a_hist;
        int bad = 0;
        for (int i = t; i < 2000; i += 256) bad |= (p[i] >> 15) & 1;
        if (bad) atomicOr(&sdet, 1);
    }
    __syncthreads();
    int isf32 = sdet;
    int bid = blockIdx.x;

    if (bid < 74){
        // ---- weight pre-swizzle, coalesced read -> LDS scatter -> coalesced write ----
        const int nck[8] = {1,8,1,8,8,24,16,8};
        const int Ks[8]  = {16,256,5,256,256,768,512,256};
        const void* srcs[8] = {w0,w1,w2,w3,w4,w5,w6,w7};
        int wi = 0, c = bid;
        while (c >= nck[wi]){ c -= nck[wi]; wi++; }
        const void* src = srcs[wi];
        int K = Ks[wi];
        u16* stage = (u16*)SMEM;      // 16 KB
        #pragma unroll 4
        for (int kk = 0; kk < 32; kk++){
            int k = c*32 + kk;
            float v = (k < K) ? ldin(src, (size_t)k*256 + t, isf32) : 0.f;  // coalesced
            int e = (t >> 4)*512 + ((kk >> 3)*16 + (t & 15))*8 + (kk & 7);
            stage[e] = f2bf(v);
        }
        __syncthreads();
        uint4* dstv = (uint4*)(wsw + (size_t)bid * 8192);
        const uint4* sv = (const uint4*)stage;
        dstv[t] = sv[t];
        dstv[t + 256] = sv[t + 256];
        dstv[t + 512] = sv[t + 512];
        dstv[t + 768] = sv[t + 768];
        return;
    }
    if (bid < 90){
        // ---- prep: s_cur (f32), pe_in (bf16 stride 32) ----
        if (bid == 74 && t == 0) dflag[0] = isf32;
        int g = (bid - 74)*256 + t;
        if (g >= NPT) return;
        int b = g / NPART, i = g - b*NPART;
        #pragma unroll
        for (int d = 0; d < 3; d++)
            s_cur[g*3 + d] = ldin(s_hist, (size_t)((b*NHIST + NHIST-1)*NPART + i)*3 + d, isf32);
        #pragma unroll
        for (int h = 0; h < NHIST; h++){
            #pragma unroll
            for (int d = 0; d < 3; d++)
                pe_in[g*32 + h*3 + d] = f2bf(ldin(s_delta, (size_t)((b*NHIST + h)*NPART + i)*3 + d, isf32));
            pe_in[g*32 + 12 + h] = f2bf(ldin(a_hist, (b*NHIST + h)*NPART + i, isf32));
        }
        #pragma unroll
        for (int k = 16; k < 32; k++) pe_in[g*32 + k] = 0;
        return;
    }
    // ---- topk: 1000 blocks, WAVE = RECEIVER (4 per block); coalesced staging ----
    float* sx = (float*)SMEM;          // 1000 f32 each (16 KB total)
    float* sy = sx + 1000;
    float* sz = sx + 2000;
    float* sa = sx + 3000;
    u32* raw  = SMEM + 4096;           // 12 KB (s slice)
    u32* rawa = SMEM + 4096 + 3072;    // 4 KB (a slice)
    int tb = bid - 90;
    int b = tb / 250, r0 = (tb % 250) * 4;
    int wid = t >> 6, lane = t & 63;
    {
        int sbase = (b*NHIST + NHIST-1)*NPART*3;
        int abase = (b*NHIST + NHIST-1)*NPART;
        if (isf32){
            const uint4* ps = (const uint4*)((const float*)s_hist + sbase);
            for (int i = t; i < 750; i += 256) ((uint4*)raw)[i] = ps[i];
            const uint4* pa = (const uint4*)((const float*)a_hist + abase);
            if (t < 250) ((uint4*)rawa)[t] = pa[t];
        } else {
            const uint4* ps = (const uint4*)((const u16*)s_hist + sbase);
            for (int i = t; i < 375; i += 256) ((uint4*)raw)[i] = ps[i];
            const uint4* pa = (const uint4*)((const u16*)a_hist + abase);
            if (t < 125) ((uint4*)rawa)[t] = pa[t];
        }
    }
    __syncthreads();
    for (int j = t; j < NPART; j += 256){
        float vx, vy, vz, va;
        if (isf32){
            vx = ((const float*)raw)[j*3+0]; vy = ((const float*)raw)[j*3+1];
            vz = ((const float*)raw)[j*3+2]; va = ((const float*)rawa)[j];
        } else {
            vx = bf2f(((const u16*)raw)[j*3+0]); vy = bf2f(((const u16*)raw)[j*3+1]);
            vz = bf2f(((const u16*)raw)[j*3+2]); va = bf2f(((const u16*)rawa)[j]);
        }
        sx[j] = vx; sy[j] = vy; sz[j] = vz; sa[j] = va;
    }
    __syncthreads();
    int i = r0 + wid;                  // receiver (wave-uniform), < 1000 always
    float xi = sx[i], yi = sy[i], zi = sz[i];
    float ai = sa[i];
    bool tool_i = ai > 0.5f;
    float thr = tool_i ? -1.0f : 0.25f;   // filtered scan: only flagged candidates enter

    float bd[NTOPK]; int bj[NTOPK];
    #pragma unroll
    for (int k = 0; k < NTOPK; k++){ bd[k] = 3.0e38f; bj[k] = 1 << 30; }
    for (int j = lane; j < NPART; j += 64){
        float dx = xi - sx[j], dy = yi - sy[j], dz = zi - sz[j];
        float d = dx*dx + dy*dy + dz*dz;
        if (d < thr && d < bd[NTOPK-1]){
            float v = d; int vj = j;
            #pragma unroll
            for (int k = 0; k < NTOPK; k++){
                bool sw = v < bd[k];
                float tv = bd[k]; int tj = bj[k];
                if (sw){ bd[k] = v; bj[k] = vj; v = tv; vj = tj; }
            }
        }
    }
    // 10-round cross-lane merge; lane r holds r-th smallest flagged candidate
    float myd = 3.0e38f; int myj = 0;
    #pragma unroll
    for (int r = 0; r < NTOPK; r++){
        float v = bd[0]; int vj = bj[0];
        #pragma unroll
        for (int s = 32; s > 0; s >>= 1){
            float ov = __shfl_xor(v, s);
            int   oj = __shfl_xor(vj, s);
            if (ov < v || (ov == v && oj < vj)){ v = ov; vj = oj; }
        }
        if (lane == r){ myd = v; myj = vj; }
        bool owner = (bd[0] == v) && (bj[0] == vj);
        if (owner){
            #pragma unroll
            for (int k = 0; k < NTOPK-1; k++){ bd[k] = bd[k+1]; bj[k] = bj[k+1]; }
            bd[NTOPK-1] = 3.0e38f; bj[NTOPK-1] = 1 << 30;
        }
    }
    // compaction: flagged lanes are the prefix; ONE atomic per block on region counter
    bool fl = (lane < NTOPK) && (myd < 0.25f);
    int cnt = __popcll(__ballot(fl));
    if (lane == 0) wcnt[wid] = cnt;
    __syncthreads();
    if (t == 0){
        int c0 = wcnt[0], c1 = wcnt[1], c2 = wcnt[2], c3 = wcnt[3];
        int reg = tb & 7;
        int bb = atomicAdd(&ecount8[reg], c0 + c1 + c2 + c3) + reg*EREG;
        wbase[0] = bb; wbase[1] = bb + c0; wbase[2] = bb + c0 + c1; wbase[3] = bb + c0 + c1 + c2;
    }
    __syncthreads();
    int base = wbase[wid];
    if (lane < NTOPK){
        int gp = b*NPART + i;
        int ce = fl ? base + lane : -1;     // prefix property: flagged lanes = 0..cnt-1
        cidx[gp*NTOPK + lane] = ce;
        if (ce >= 0){
            int j = myj;
            csend[ce] = b*NPART + j;
            u32 q0 = (u32)f2bf(ai)        | ((u32)f2bf(sa[j])      << 16);
            u32 q1 = (u32)f2bf(xi - sx[j]) | ((u32)f2bf(yi - sy[j]) << 16);
            u32 q2 = (u32)f2bf(zi - sz[j]);
            uint4 v0 = {q0, q1, q2, 0};
            uint4 zz = {0, 0, 0, 0};
            uint4* rp = (uint4*)(re_in + (size_t)ce*32);
            rp[0] = v0; rp[1] = zz; rp[2] = zz; rp[3] = zz;
        }
    }
}

// =============== fused edge chain (32-row tiles, 8-region COMPACTED) + particle encoder ===============
// blocks 0..(8*NRT-1): relation chain (region = bid/NRT, per-region early-exit);
// blocks 8*NRT..8*NRT+124: particle encoder (pe0->pe1), 32 rows each.
// 32-row tiles: LDS 2x16KB ping-pong + 2KB stage = 34KB -> ~4 blocks/CU co-resident.
__global__ __launch_bounds__(256) void k_edge(
    const u16* __restrict__ re_in, const u16* __restrict__ pe_in,
    const u16* __restrict__ W0, const u16* __restrict__ W1,
    const u16* __restrict__ W2, const u16* __restrict__ W3,
    const u16* __restrict__ PW0, const u16* __restrict__ PW1,
    const void* __restrict__ B0, const void* __restrict__ B1,
    const void* __restrict__ B2,
    const void* __restrict__ PB0, const void* __restrict__ PB1,
    const int* __restrict__ dflag, const int* __restrict__ ecount8,
    u16* __restrict__ Eout, u16* __restrict__ penc)
{
    __shared__ u16 H1[32*256];   // 16 KB
    __shared__ u16 H2[32*256];   // 16 KB
    __shared__ u16 S[32*32];     // 2 KB input stage
    int t = threadIdx.x, lane = t & 63, wave = t >> 6;
    int wm = wave >> 1, wn = wave & 1;
    int isf32 = dflag[0];
    int l15 = lane & 15, l4 = lane >> 4;

    f4v acc[8];
    b8v af, bfr[8];
    auto zacc = [&](){
        #pragma unroll
        for (int j = 0; j < 8; j++) acc[j] = {0.f,0.f,0.f,0.f};
    };
    auto rdW = [&](const u16* W, int kc){
        #pragma unroll
        for (int j = 0; j < 8; j++)
            bfr[j] = *(const b8v*)(W + (size_t)kc*8192 + ((wn*8 + j)*64 + lane)*8);
    };
    auto domf = [&](){
        #pragma unroll
        for (int j = 0; j < 8; j++)
            acc[j] = __builtin_amdgcn_mfma_f32_16x16x32_bf16(af, bfr[j], acc[j], 0, 0, 0);
    };
    // layer over 32x256 input in LDS (key &31 swizzle)
    auto layer = [&](const u16* Hin, const u16* Wg){
        zacc();
        for (int kc = 0; kc < 8; kc++){
            rdW(Wg, kc);
            int R = wm*16 + l15;
            int up = (kc*4 + l4) ^ (R & 31);
            af = *(const b8v*)&Hin[R*256 + up*8];
            domf();
        }
    };
    auto epiLDS = [&](u16* Hout, const void* Wb){
        #pragma unroll
        for (int j = 0; j < 8; j++){
            int col = (wn*8 + j)*16 + l15;
            float bias = ldin(Wb, col, isf32);
            int rb = wm*16 + l4*4;
            #pragma unroll
            for (int r = 0; r < 4; r++){
                float v = acc[j][r] + bias;
                v = v > 0.f ? v : 0.f;
                int rr = rb + r;
                int up = (col >> 3) ^ (rr & 31);
                Hout[rr*256 + up*8 + (col & 7)] = f2bf(v);
            }
        }
    };

    if (blockIdx.x >= 8*NRT){
        // ---------- particle encoder ----------
        int row0 = (blockIdx.x - 8*NRT) * 32;
        if (t < 128){
            int row = t >> 2, q = t & 3;
            int rg = row0 + row;
            uint4 v = *(const uint4*)(pe_in + (size_t)rg*32 + q*8);
            int up = q ^ (row & 3);
            *(uint4*)&S[row*32 + up*8] = v;
        }
        __syncthreads();
        zacc();
        {
            rdW(PW0, 0);
            int R = wm*16 + l15;
            int up = l4 ^ (R & 3);
            af = *(const b8v*)&S[R*32 + up*8];
            domf();
        }
        epiLDS(H1, PB0);
        __syncthreads();
        layer(H1, PW1);
        #pragma unroll
        for (int j = 0; j < 8; j++){
            int col = (wn*8 + j)*16 + l15;
            float bias = ldin(PB1, col, isf32);
            int rb = row0 + wm*16 + l4*4;
            #pragma unroll
            for (int r = 0; r < 4; r++){
                int row = rb + r;
                float v = acc[j][r] + bias;
                penc[(size_t)row*256 + col] = f2bf(v > 0.f ? v : 0.f);
            }
        }
        return;
    }

    // ---------- relation chain on 8-region compacted edges (32-row tiles) ----------
    int region = blockIdx.x / NRT;
    int local  = blockIdx.x - region*NRT;
    int ec = ecount8[region];
    if (local*32 >= ec) return;      // whole block exits (uniform, before any barrier)
    int row0 = region*EREG + local*32;
    if (t < 128){
        int row = t >> 2, q = t & 3;
        int rg = row0 + row; if (rg >= NET) rg = NET - 1;
        uint4 v = *(const uint4*)(re_in + (size_t)rg*32 + q*8);
        int up = q ^ (row & 3);
        *(uint4*)&S[row*32 + up*8] = v;
    }
    __syncthreads();

    // L0: S (K=32) -> H1
    zacc();
    {
        rdW(W0, 0);
        int R = wm*16 + l15;
        int up = l4 ^ (R & 3);
        af = *(const b8v*)&S[R*32 + up*8];
        domf();
    }
    epiLDS(H1, B0);
    __syncthreads();
    layer(H1, W1); epiLDS(H2, B1);
    __syncthreads();
    layer(H2, W2); epiLDS(H1, B2);
    __syncthreads();
    layer(H1, W3);
    // Erel: linear, no bias -> global (compacted rows)
    #pragma unroll
    for (int j = 0; j < 8; j++){
        int col = (wn*8 + j)*16 + l15;
        #pragma unroll
        for (int i = 0; i < 2; i++);
        int rb = row0 + wm*16 + l4*4;
        #pragma unroll
        for (int r = 0; r < 4; r++){
            int row = rb + r;
            if (row < NET) Eout[(size_t)row*256 + col] = f2bf(acc[j][r]);
        }
    }
}

// =============== MFMA GEMM (register-staged, colhalf): PrPs dual-bank ===============
template<int AMODE, int ACT, int TM>
__global__ __launch_bounds__(256) void k_mgemm3(
    const u16* __restrict__ A, const u16* __restrict__ X1,
    const u16* __restrict__ Wsw, const void* __restrict__ Wb,
    const int* __restrict__ dflag,
    const u16* __restrict__ res,
    u16* __restrict__ C, int M, int K, int lda, int nrb)
{
    __shared__ u16 a_lds[TM*32];
    int t = threadIdx.x;
    int lane = t & 63, wave = t >> 6;
    int wm = wave >> 1, wn = wave & 1;
    int bid = blockIdx.x;
    if (AMODE == 3){
        int bank = bid / (nrb*2); bid -= bank*(nrb*2);
        Wsw += (size_t)bank * (8*8192);
        C   += (size_t)bank * NPT * 256;
    }
    int rowblk = bid >> 1, ch = bid & 1;
    int row0 = rowblk * TM;
    constexpr int NSLOT = TM*4;

    f4v acc[TM/32][4];
    #pragma unroll
    for (int i = 0; i < TM/32; i++)
        #pragma unroll
        for (int j = 0; j < 4; j++) acc[i][j] = {0.f,0.f,0.f,0.f};

    int nkc = K >> 5;
    for (int kc = 0; kc < nkc; kc++){
        int kbase = kc * 32;
        uint4 ra;
        if (t < NSLOT){
            int row = t >> 2, up = t & 3;
            int q = up ^ ((row >> 1) & 3);
            int rg = row0 + row; if (rg >= M) rg = M - 1;
            int kg = kbase + q*8;
            const u16* src;
            if (AMODE == 2){
                if (kg < 256) src = A  + (size_t)rg * 256 + kg;
                else          src = X1 + (size_t)rg * 256 + (kg - 256);
            } else {
                src = A + (size_t)rg * lda + kg;
            }
            ra = *(const uint4*)src;
        }
        __syncthreads();
        if (t < NSLOT) ((uint4*)a_lds)[t] = ra;
        __syncthreads();
        b8v af[TM/32], bfr[4];
        int c4 = lane >> 4;
        #pragma unroll
        for (int i = 0; i < TM/32; i++){
            int R = wm*(TM/2) + i*16 + (lane & 15);
            int up = c4 ^ ((R >> 1) & 3);
            af[i] = *(const b8v*)&a_lds[R*32 + up*8];
        }
        #pragma unroll
        for (int j = 0; j < 4; j++)
            bfr[j] = *(const b8v*)(Wsw + (size_t)kc*8192 + ch*4096 + ((wn*4 + j)*64 + lane)*8);
        #pragma unroll
        for (int i = 0; i < TM/32; i++)
            #pragma unroll
            for (int j = 0; j < 4; j++)
                acc[i][j] = __builtin_amdgcn_mfma_f32_16x16x32_bf16(af[i], bfr[j], acc[i][j], 0, 0, 0);
    }
    int isf32 = (ACT >= 1) ? dflag[0] : 0;
    #pragma unroll
    for (int j = 0; j < 4; j++){
        int col = ch*128 + (wn*4 + j)*16 + (lane & 15);
        float bias = (ACT >= 1) ? ldin(Wb, col, isf32) : 0.f;
        #pragma unroll
        for (int i = 0; i < TM/32; i++){
            int rbase = row0 + wm*(TM/2) + i*16 + (lane >> 4)*4;
            #pragma unroll
            for (int r = 0; r < 4; r++){
                int row = rbase + r;
                if (row < M){
                    float v = acc[i][j][r] + bias;
                    if (ACT == 2) v += bf2f(res[(size_t)row*256 + col]);
                    if (ACT >= 1) v = v > 0.f ? v : 0.f;
                    C[(size_t)row*256 + col] = f2bf(v);
                }
            }
        }
    }
}

// =============== edge assembly + relu + aggregation over COMPACTED edges ===============
__global__ void k_rpagg(const u16* __restrict__ Erel, const u16* __restrict__ Pr,
                        const u16* __restrict__ Ps,
                        const int* __restrict__ cidx, const int* __restrict__ csend,
                        const void* __restrict__ rp_b,
                        const int* __restrict__ dflag, u16* __restrict__ agg)
{
    int g = blockIdx.x, c = threadIdx.x;
    int isf32 = dflag[0];
    float bias = ldin(rp_b, c, isf32);
    float pr = bf2f(Pr[(size_t)g*256 + c]);
    float s = 0.f;
    #pragma unroll
    for (int k = 0; k < NTOPK; k++){
        int ce = cidx[g*NTOPK + k];
        if (ce >= 0){
            float v = bf2f(Erel[(size_t)ce*256 + c]) + pr
                    + bf2f(Ps[(size_t)csend[ce]*256 + c]) + bias;
            s += v > 0.f ? v : 0.f;
        }
    }
    agg[(size_t)g*256 + c] = f2bf(s);
}

// =============== fused predictor: GEMM(K=256,relu) + GEMV(256->3) + s_cur ===============
__global__ __launch_bounds__(256) void k_predfuse(
    const u16* __restrict__ peff, const u16* __restrict__ W0,
    const void* __restrict__ B0, const void* __restrict__ w1,
    const void* __restrict__ b1, const int* __restrict__ dflag,
    const float* __restrict__ s_cur, void* __restrict__ out)
{
    __shared__ u16 a_lds[32*32];
    __shared__ u16 H[32*264];
    __shared__ float sw1[768];
    __shared__ float sb1[3];
    int t = threadIdx.x, lane = t & 63, wave = t >> 6;
    int wm = wave >> 1, wn = wave & 1;
    int row0 = blockIdx.x * 32;
    int isf32 = dflag[0];
    #pragma unroll
    for (int i = 0; i < 3; i++) sw1[t + i*256] = ldin(w1, t + i*256, isf32);
    if (t < 3) sb1[t] = ldin(b1, t, isf32);

    f4v acc[8];
    #pragma unroll
    for (int j = 0; j < 8; j++) acc[j] = {0.f,0.f,0.f,0.f};
    for (int kc = 0; kc < 8; kc++){
        uint4 ra;
        if (t < 128){
            int row = t >> 2, up = t & 3;
            int q = up ^ ((row >> 1) & 3);
            int rg = row0 + row;
            ra = *(const uint4*)(peff + (size_t)rg*256 + kc*32 + q*8);
        }
        __syncthreads();
        if (t < 128) ((uint4*)a_lds)[t] = ra;
        __syncthreads();
        b8v af, bfr[8];
        int R = wm*16 + (lane & 15);
        int up = (lane >> 4) ^ ((R >> 1) & 3);
        af = *(const b8v*)&a_lds[R*32 + up*8];
        #pragma unroll
        for (int j = 0; j < 8; j++)
            bfr[j] = *(const b8v*)(W0 + (size_t)kc*8192 + ((wn*8 + j)*64 + lane)*8);
        #pragma unroll
        for (int j = 0; j < 8; j++)
            acc[j] = __builtin_amdgcn_mfma_f32_16x16x32_bf16(af, bfr[j], acc[j], 0, 0, 0);
    }
    #pragma unroll
    for (int j = 0; j < 8; j++){
        int col = (wn*8 + j)*16 + (lane & 15);
        float bias = ldin(B0, col, isf32);
        int rb = wm*16 + (lane >> 4)*4;
        #pragma unroll
        for (int r = 0; r < 4; r++){
            float v = acc[j][r] + bias;
            H[(rb + r)*264 + col] = f2bf(v > 0.f ? v : 0.f);
        }
    }
    __syncthreads();
    int row = t >> 3, dd = t & 7;
    if (dd < 3){
        int g = row0 + row;
        float s = sb1[dd] + s_cur[g*3 + dd];
        const u16* hr = &H[row*264];
        #pragma unroll 8
        for (int k = 0; k < 256; k++)
            s += bf2f(hr[k]) * sw1[k*3 + dd];
        if (isf32) ((float*)out)[g*3 + dd] = s;
        else       ((u16*)out)[g*3 + dd]   = f2bf(s);
    }
}

extern "C" void kernel_launch(void* const* d_in, const int* in_sizes, int n_in,
                              void* d_out, int out_size, void* d_ws, size_t ws_size,
                              hipStream_t stream) {
    const void* a_hist = d_in[0];
    const void* s_hist = d_in[1];
    const void* s_delta= d_in[2];
    const void* pe_w0 = d_in[3];  const void* pe_b0 = d_in[4];
    const void* pe_w1 = d_in[5];  const void* pe_b1 = d_in[6];
    const void* re_w0 = d_in[7];  const void* re_b0 = d_in[8];
    const void* re_w1 = d_in[9];  const void* re_b1 = d_in[10];
    const void* re_w2 = d_in[11]; const void* re_b2 = d_in[12];
    const void* rp_w  = d_in[13]; const void* rp_b  = d_in[14];
    const void* pp_w  = d_in[15]; const void* pp_b  = d_in[16];
    const void* pr_w0 = d_in[17]; const void* pr_b0 = d_in[18];
    const void* pr_w1 = d_in[19]; const void* pr_b1 = d_in[20];

    char* base = (char*)d_ws;
    size_t off = 0;
    auto alloc = [&](size_t bytes) -> char* {
        char* p = base + off;
        off += (bytes + 255) & ~(size_t)255;
        return p;
    };
    int*   dflag = (int*)  alloc(16);
    int*   ecount8 = (int*)alloc(64);
    float* s_cur = (float*)alloc(NPT*3*4);
    int*   cidx  = (int*)  alloc(NET*4);
    int*   csend = (int*)  alloc(NET*4);
    u16* pe_in = (u16*)alloc((size_t)NPT*32*2);
    u16* re_in = (u16*)alloc((size_t)NET*32*2);
    u16* penc  = (u16*)alloc((size_t)NPT*256*2);
    u16* aggB  = (u16*)alloc((size_t)NPT*256*2);
    u16* peffA = (u16*)alloc((size_t)NPT*256*2);
    u16* peffB = (u16*)alloc((size_t)NPT*256*2);
    u16* PrPs  = (u16*)alloc((size_t)2*NPT*256*2);
    u16* Erel  = (u16*)alloc((size_t)NET*256*2);
    u16* wsw   = (u16*)alloc((size_t)74*8192*2);

    // swizzled-weight bases (chunks: pe_w0 1, pe_w1 8, re_w0 1, re_w1 8, re_w2 8, rp_w 24, pp_w 16, pr_w0 8)
    u16* sw_pe0 = wsw + (size_t) 0*8192;
    u16* sw_pe1 = wsw + (size_t) 1*8192;
    u16* sw_re0 = wsw + (size_t) 9*8192;
    u16* sw_re1 = wsw + (size_t)10*8192;
    u16* sw_re2 = wsw + (size_t)18*8192;
    u16* sw_rp  = wsw + (size_t)26*8192;   // 0..7 rel | 8..15 recv | 16..23 send
    u16* sw_pp  = wsw + (size_t)50*8192;
    u16* sw_pr0 = wsw + (size_t)66*8192;

    u16* Pr = PrPs;
    u16* Ps = PrPs + (size_t)NPT*256;

    const int nrbP = 125;           // ceil(4000/32)
    const int gP  = nrbP*2;         // 250 (TM=32, colhalf)

    hipMemsetAsync(ecount8, 0, 32, stream);

    k_setup<<<1090, 256, 0, stream>>>(a_hist, s_hist, s_delta,
        pe_w0, pe_w1, re_w0, re_w1, re_w2, rp_w, pp_w, pr_w0,
        wsw, dflag, s_cur, pe_in, ecount8, cidx, csend, re_in);

    k_edge<<<8*NRT + 125, 256, 0, stream>>>(re_in, pe_in,
        sw_re0, sw_re1, sw_re2, sw_rp, sw_pe0, sw_pe1,
        re_b0, re_b1, re_b2, pe_b0, pe_b1, dflag, ecount8, Erel, penc);

    // propagation step 1
    k_mgemm3<3,0,32><<<2*gP, 256, 0, stream>>>(penc, nullptr, sw_rp + (size_t)8*8192, nullptr, dflag, nullptr, PrPs, NPT, 256, 256, nrbP);
    k_rpagg<<<NPT, 256, 0, stream>>>(Erel, Pr, Ps, cidx, csend, rp_b, dflag, aggB);
    k_mgemm3<2,2,32><<<gP, 256, 0, stream>>>(penc, aggB, sw_pp, pp_b, dflag, penc, peffA, NPT, 512, 0, nrbP);
    // step 2
    k_mgemm3<3,0,32><<<2*gP, 256, 0, stream>>>(peffA, nullptr, sw_rp + (size_t)8*8192, nullptr, dflag, nullptr, PrPs, NPT, 256, 256, nrbP);
    k_rpagg<<<NPT, 256, 0, stream>>>(Erel, Pr, Ps, cidx, csend, rp_b, dflag, aggB);
    k_mgemm3<2,2,32><<<gP, 256, 0, stream>>>(penc, aggB, sw_pp, pp_b, dflag, peffA, peffB, NPT, 512, 0, nrbP);
    // step 3
    k_mgemm3<3,0,32><<<2*gP, 256, 0, stream>>>(peffB, nullptr, sw_rp + (size_t)8*8192, nullptr, dflag, nullptr, PrPs, NPT, 256, 256, nrbP);
    k_rpagg<<<NPT, 256, 0, stream>>>(Erel, Pr, Ps, cidx, csend, rp_b, dflag, aggB);
    k_mgemm3<2,2,32><<<gP, 256, 0, stream>>>(penc, aggB, sw_pp, pp_b, dflag, peffB, peffA, NPT, 512, 0, nrbP);

    // fused predictor + output
    k_predfuse<<<nrbP, 256, 0, stream>>>(peffA, sw_pr0, pr_b0, pr_w1, pr_b1, dflag, s_cur, (void*)d_out);
}

// Round 17
// 288.111 us; speedup vs baseline: 1.0403x; 1.0403x over previous
//
#include <hip/hip_runtime.h>
#include <hip/hip_bf16.h>

typedef unsigned short u16;
typedef unsigned int u32;

#define BATCH 4
#define NHIST 4
#define NPART 1000
#define NTOPK 10
#define NPT (BATCH*NPART)     // 4000 particles total
#define NET (NPT*NTOPK)       // 40000 edges capacity
#define EREG 5000             // per-region edge capacity (8 regions)
#define NRT 157               // relation tiles per region (ceil(EREG/32))

typedef __bf16 b8v __attribute__((ext_vector_type(8)));
typedef float  f4v __attribute__((ext_vector_type(4)));

__device__ __forceinline__ float bf2f(u16 b){
    return __uint_as_float(((u32)b) << 16);
}
__device__ __forceinline__ u16 f2bf(float f){
    u32 u = __float_as_uint(f);
    u32 r = u + 0x7FFF + ((u >> 16) & 1);  // RNE
    return (u16)(r >> 16);
}
__device__ __forceinline__ float ldin(const void* p, size_t i, int isf32){
    return isf32 ? ((const float*)p)[i] : bf2f(((const u16*)p)[i]);
}

// =============== setup: dtype-probe + weight swizzle + prep + topk+compact ===============
// grid 1090: blocks 0..73 weight swizzle, 74..89 prep, 90..1089 topk (wave = receiver).
__global__ __launch_bounds__(256) void k_setup(
    const void* __restrict__ a_hist, const void* __restrict__ s_hist,
    const void* __restrict__ s_delta,
    const void* w0, const void* w1, const void* w2, const void* w3,
    const void* w4, const void* w5, const void* w6, const void* w7,
    u16* __restrict__ wsw, int* __restrict__ dflag,
    float* __restrict__ s_cur, u16* __restrict__ pe_in,
    int* __restrict__ ecount8, int* __restrict__ cidx, int* __restrict__ csend,
    u16* __restrict__ re_in)
{
    __shared__ u32 SMEM[8192];
    __shared__ int sdet;
    __shared__ int wcnt[4], wbase[4];
    int t = threadIdx.x;
    if (t == 0) sdet = 0;
    __syncthreads();
    {
        const u16* p = (const u16*)a_hist;
        int bad = 0;
        for (int i = t; i < 2000; i += 256) bad |= (p[i] >> 15) & 1;
        if (bad) atomicOr(&sdet, 1);
    }
    __syncthreads();
    int isf32 = sdet;
    int bid = blockIdx.x;

    if (bid < 74){
        const int nck[8] = {1,8,1,8,8,24,16,8};
        const int Ks[8]  = {16,256,5,256,256,768,512,256};
        const void* srcs[8] = {w0,w1,w2,w3,w4,w5,w6,w7};
        int wi = 0, c = bid;
        while (c >= nck[wi]){ c -= nck[wi]; wi++; }
        const void* src = srcs[wi];
        int K = Ks[wi];
        u16* stage = (u16*)SMEM;
        #pragma unroll 4
        for (int kk = 0; kk < 32; kk++){
            int k = c*32 + kk;
            float v = (k < K) ? ldin(src, (size_t)k*256 + t, isf32) : 0.f;
            int e = (t >> 4)*512 + ((kk >> 3)*16 + (t & 15))*8 + (kk & 7);
            stage[e] = f2bf(v);
        }
        __syncthreads();
        uint4* dstv = (uint4*)(wsw + (size_t)bid * 8192);
        const uint4* sv = (const uint4*)stage;
        dstv[t] = sv[t];
        dstv[t + 256] = sv[t + 256];
        dstv[t + 512] = sv[t + 512];
        dstv[t + 768] = sv[t + 768];
        return;
    }
    if (bid < 90){
        if (bid == 74 && t == 0) dflag[0] = isf32;
        int g = (bid - 74)*256 + t;
        if (g >= NPT) return;
        int b = g / NPART, i = g - b*NPART;
        #pragma unroll
        for (int d = 0; d < 3; d++)
            s_cur[g*3 + d] = ldin(s_hist, (size_t)((b*NHIST + NHIST-1)*NPART + i)*3 + d, isf32);
        #pragma unroll
        for (int h = 0; h < NHIST; h++){
            #pragma unroll
            for (int d = 0; d < 3; d++)
                pe_in[g*32 + h*3 + d] = f2bf(ldin(s_delta, (size_t)((b*NHIST + h)*NPART + i)*3 + d, isf32));
            pe_in[g*32 + 12 + h] = f2bf(ldin(a_hist, (b*NHIST + h)*NPART + i, isf32));
        }
        #pragma unroll
        for (int k = 16; k < 32; k++) pe_in[g*32 + k] = 0;
        return;
    }
    // ---- topk: 1000 blocks, WAVE = RECEIVER (4/block) ----
    float* sx = (float*)SMEM;
    float* sy = sx + 1000;
    float* sz = sx + 2000;
    float* sa = sx + 3000;
    u32* raw  = SMEM + 4096;
    u32* rawa = SMEM + 4096 + 3072;
    int tb = bid - 90;
    int b = tb / 250, r0 = (tb % 250) * 4;
    int wid = t >> 6, lane = t & 63;
    {
        int sbase = (b*NHIST + NHIST-1)*NPART*3;
        int abase = (b*NHIST + NHIST-1)*NPART;
        if (isf32){
            const uint4* ps = (const uint4*)((const float*)s_hist + sbase);
            for (int i = t; i < 750; i += 256) ((uint4*)raw)[i] = ps[i];
            const uint4* pa = (const uint4*)((const float*)a_hist + abase);
            if (t < 250) ((uint4*)rawa)[t] = pa[t];
        } else {
            const uint4* ps = (const uint4*)((const u16*)s_hist + sbase);
            for (int i = t; i < 375; i += 256) ((uint4*)raw)[i] = ps[i];
            const uint4* pa = (const uint4*)((const u16*)a_hist + abase);
            if (t < 125) ((uint4*)rawa)[t] = pa[t];
        }
    }
    __syncthreads();
    for (int j = t; j < NPART; j += 256){
        float vx, vy, vz, va;
        if (isf32){
            vx = ((const float*)raw)[j*3+0]; vy = ((const float*)raw)[j*3+1];
            vz = ((const float*)raw)[j*3+2]; va = ((const float*)rawa)[j];
        } else {
            vx = bf2f(((const u16*)raw)[j*3+0]); vy = bf2f(((const u16*)raw)[j*3+1]);
            vz = bf2f(((const u16*)raw)[j*3+2]); va = bf2f(((const u16*)rawa)[j]);
        }
        sx[j] = vx; sy[j] = vy; sz[j] = vz; sa[j] = va;
    }
    __syncthreads();
    int i = r0 + wid;
    float xi = sx[i], yi = sy[i], zi = sz[i];
    float ai = sa[i];
    bool tool_i = ai > 0.5f;
    float thr = tool_i ? -1.0f : 0.25f;

    float bd[NTOPK]; int bj[NTOPK];
    #pragma unroll
    for (int k = 0; k < NTOPK; k++){ bd[k] = 3.0e38f; bj[k] = 1 << 30; }
    for (int j = lane; j < NPART; j += 64){
        float dx = xi - sx[j], dy = yi - sy[j], dz = zi - sz[j];
        float d = dx*dx + dy*dy + dz*dz;
        if (d < thr && d < bd[NTOPK-1]){
            float v = d; int vj = j;
            #pragma unroll
            for (int k = 0; k < NTOPK; k++){
                bool sw = v < bd[k];
                float tv = bd[k]; int tj = bj[k];
                if (sw){ bd[k] = v; bj[k] = vj; v = tv; vj = tj; }
            }
        }
    }
    float myd = 3.0e38f; int myj = 0;
    #pragma unroll
    for (int r = 0; r < NTOPK; r++){
        float v = bd[0]; int vj = bj[0];
        #pragma unroll
        for (int s = 32; s > 0; s >>= 1){
            float ov = __shfl_xor(v, s);
            int   oj = __shfl_xor(vj, s);
            if (ov < v || (ov == v && oj < vj)){ v = ov; vj = oj; }
        }
        if (lane == r){ myd = v; myj = vj; }
        bool owner = (bd[0] == v) && (bj[0] == vj);
        if (owner){
            #pragma unroll
            for (int k = 0; k < NTOPK-1; k++){ bd[k] = bd[k+1]; bj[k] = bj[k+1]; }
            bd[NTOPK-1] = 3.0e38f; bj[NTOPK-1] = 1 << 30;
        }
    }
    bool fl = (lane < NTOPK) && (myd < 0.25f);
    int cnt = __popcll(__ballot(fl));
    if (lane == 0) wcnt[wid] = cnt;
    __syncthreads();
    if (t == 0){
        int c0 = wcnt[0], c1 = wcnt[1], c2 = wcnt[2], c3 = wcnt[3];
        int reg = tb & 7;
        int bb = atomicAdd(&ecount8[reg], c0 + c1 + c2 + c3) + reg*EREG;
        wbase[0] = bb; wbase[1] = bb + c0; wbase[2] = bb + c0 + c1; wbase[3] = bb + c0 + c1 + c2;
    }
    __syncthreads();
    int base = wbase[wid];
    if (lane < NTOPK){
        int gp = b*NPART + i;
        int ce = fl ? base + lane : -1;
        cidx[gp*NTOPK + lane] = ce;
        if (ce >= 0){
            int j = myj;
            csend[ce] = b*NPART + j;
            u32 q0 = (u32)f2bf(ai)        | ((u32)f2bf(sa[j])      << 16);
            u32 q1 = (u32)f2bf(xi - sx[j]) | ((u32)f2bf(yi - sy[j]) << 16);
            u32 q2 = (u32)f2bf(zi - sz[j]);
            uint4 v0 = {q0, q1, q2, 0};
            uint4 zz = {0, 0, 0, 0};
            uint4* rp = (uint4*)(re_in + (size_t)ce*32);
            rp[0] = v0; rp[1] = zz; rp[2] = zz; rp[3] = zz;
        }
    }
}

// =============== fused edge chain + particle encoder (+ Pr0/Ps0) ===============
// blocks 0..(8*NRT-1): relation chain (region = bid/NRT, per-region early-exit);
// blocks 8*NRT..: particle encoder pe0->pe1, then Pr0/Ps0 = penc @ rp_w{recv,send}.
__global__ __launch_bounds__(256) void k_edge(
    const u16* __restrict__ re_in, const u16* __restrict__ pe_in,
    const u16* __restrict__ W0, const u16* __restrict__ W1,
    const u16* __restrict__ W2, const u16* __restrict__ W3,
    const u16* __restrict__ PW0, const u16* __restrict__ PW1,
    const u16* __restrict__ WrpB,
    const void* __restrict__ B0, const void* __restrict__ B1,
    const void* __restrict__ B2,
    const void* __restrict__ PB0, const void* __restrict__ PB1,
    const int* __restrict__ dflag, const int* __restrict__ ecount8,
    u16* __restrict__ Eout, u16* __restrict__ penc,
    u16* __restrict__ Pr, u16* __restrict__ Ps)
{
    __shared__ u16 H1[32*256];
    __shared__ u16 H2[32*256];
    __shared__ u16 S[32*32];
    int t = threadIdx.x, lane = t & 63, wave = t >> 6;
    int wm = wave >> 1, wn = wave & 1;
    int isf32 = dflag[0];
    int l15 = lane & 15, l4 = lane >> 4;

    f4v acc[8];
    b8v af, bfr[8];
    auto zacc = [&](){
        #pragma unroll
        for (int j = 0; j < 8; j++) acc[j] = {0.f,0.f,0.f,0.f};
    };
    auto rdW = [&](const u16* W, int kc){
        #pragma unroll
        for (int j = 0; j < 8; j++)
            bfr[j] = *(const b8v*)(W + (size_t)kc*8192 + ((wn*8 + j)*64 + lane)*8);
    };
    auto domf = [&](){
        #pragma unroll
        for (int j = 0; j < 8; j++)
            acc[j] = __builtin_amdgcn_mfma_f32_16x16x32_bf16(af, bfr[j], acc[j], 0, 0, 0);
    };
    auto layer = [&](const u16* Hin, const u16* Wg){
        zacc();
        for (int kc = 0; kc < 8; kc++){
            rdW(Wg, kc);
            int R = wm*16 + l15;
            int up = (kc*4 + l4) ^ (R & 31);
            af = *(const b8v*)&Hin[R*256 + up*8];
            domf();
        }
    };
    auto epiLDS = [&](u16* Hout, const void* Wb){
        #pragma unroll
        for (int j = 0; j < 8; j++){
            int col = (wn*8 + j)*16 + l15;
            float bias = ldin(Wb, col, isf32);
            int rb = wm*16 + l4*4;
            #pragma unroll
            for (int r = 0; r < 4; r++){
                float v = acc[j][r] + bias;
                v = v > 0.f ? v : 0.f;
                int rr = rb + r;
                int up = (col >> 3) ^ (rr & 31);
                Hout[rr*256 + up*8 + (col & 7)] = f2bf(v);
            }
        }
    };
    auto stLin = [&](u16* C, int row0){
        #pragma unroll
        for (int j = 0; j < 8; j++){
            int col = (wn*8 + j)*16 + l15;
            int rb = row0 + wm*16 + l4*4;
            #pragma unroll
            for (int r = 0; r < 4; r++)
                C[(size_t)(rb + r)*256 + col] = f2bf(acc[j][r]);
        }
    };

    if (blockIdx.x >= 8*NRT){
        // ---------- particle encoder + Pr0/Ps0 ----------
        int row0 = (blockIdx.x - 8*NRT) * 32;
        if (t < 128){
            int row = t >> 2, q = t & 3;
            int rg = row0 + row;
            uint4 v = *(const uint4*)(pe_in + (size_t)rg*32 + q*8);
            int up = q ^ (row & 3);
            *(uint4*)&S[row*32 + up*8] = v;
        }
        __syncthreads();
        zacc();
        {
            rdW(PW0, 0);
            int R = wm*16 + l15;
            int up = l4 ^ (R & 3);
            af = *(const b8v*)&S[R*32 + up*8];
            domf();
        }
        epiLDS(H1, PB0);
        __syncthreads();
        layer(H1, PW1);
        // penc: global store + LDS (H2) for Pr/Ps
        #pragma unroll
        for (int j = 0; j < 8; j++){
            int col = (wn*8 + j)*16 + l15;
            float bias = ldin(PB1, col, isf32);
            int rb = wm*16 + l4*4;
            #pragma unroll
            for (int r = 0; r < 4; r++){
                int rr = rb + r;
                float v = acc[j][r] + bias;
                v = v > 0.f ? v : 0.f;
                penc[(size_t)(row0 + rr)*256 + col] = f2bf(v);
                int up = (col >> 3) ^ (rr & 31);
                H2[rr*256 + up*8 + (col & 7)] = f2bf(v);
            }
        }
        __syncthreads();
        layer(H2, WrpB);                      stLin(Pr, row0);
        layer(H2, WrpB + (size_t)8*8192);     stLin(Ps, row0);
        return;
    }

    // ---------- relation chain on 8-region compacted edges (32-row tiles) ----------
    int region = blockIdx.x / NRT;
    int local  = blockIdx.x - region*NRT;
    int ec = ecount8[region];
    if (local*32 >= ec) return;
    int row0 = region*EREG + local*32;
    if (t < 128){
        int row = t >> 2, q = t & 3;
        int rg = row0 + row; if (rg >= NET) rg = NET - 1;
        uint4 v = *(const uint4*)(re_in + (size_t)rg*32 + q*8);
        int up = q ^ (row & 3);
        *(uint4*)&S[row*32 + up*8] = v;
    }
    __syncthreads();

    zacc();
    {
        rdW(W0, 0);
        int R = wm*16 + l15;
        int up = l4 ^ (R & 3);
        af = *(const b8v*)&S[R*32 + up*8];
        domf();
    }
    epiLDS(H1, B0);
    __syncthreads();
    layer(H1, W1); epiLDS(H2, B1);
    __syncthreads();
    layer(H2, W2); epiLDS(H1, B2);
    __syncthreads();
    layer(H1, W3);
    stLin(Eout, row0);
}

// =============== edge assembly + relu + aggregation over COMPACTED edges ===============
__global__ void k_rpagg(const u16* __restrict__ Erel, const u16* __restrict__ Pr,
                        const u16* __restrict__ Ps,
                        const int* __restrict__ cidx, const int* __restrict__ csend,
                        const void* __restrict__ rp_b,
                        const int* __restrict__ dflag, u16* __restrict__ agg)
{
    int g = blockIdx.x, c = threadIdx.x;
    int isf32 = dflag[0];
    float bias = ldin(rp_b, c, isf32);
    float pr = bf2f(Pr[(size_t)g*256 + c]);
    float s = 0.f;
    #pragma unroll
    for (int k = 0; k < NTOPK; k++){
        int ce = cidx[g*NTOPK + k];
        if (ce >= 0){
            float v = bf2f(Erel[(size_t)ce*256 + c]) + pr
                    + bf2f(Ps[(size_t)csend[ce]*256 + c]) + bias;
            s += v > 0.f ? v : 0.f;
        }
    }
    agg[(size_t)g*256 + c] = f2bf(s);
}

// =============== fused PP GEMM + {PrPs | predictor} ===============
// 125 blocks x 32 rows, full N=256. PP: K=512 concat [penc|aggB] + bias + res + relu.
// MODE 0: also Pr/Ps = peff @ rp_w{recv,send} from the LDS-resident peff tile.
// MODE 1: predictor (pr0 GEMM + GEMV 256->3 + s_cur) from the LDS tile; no global peff.
template<int MODE>
__global__ __launch_bounds__(256) void k_ppfuse2(
    const u16* __restrict__ penc, const u16* __restrict__ aggB,
    const u16* __restrict__ Wpp, const void* __restrict__ Bpp,
    const u16* __restrict__ res, u16* __restrict__ peff_out,
    const u16* __restrict__ WrpB, u16* __restrict__ Pr, u16* __restrict__ Ps,
    const u16* __restrict__ Wpr0, const void* __restrict__ Bpr0,
    const void* __restrict__ w1, const void* __restrict__ b1,
    const float* __restrict__ s_cur, void* __restrict__ out,
    const int* __restrict__ dflag)
{
    constexpr int SMW = (MODE == 1) ? (1024 + 8192 + 8448 + 1536 + 8) : (1024 + 8192);
    __shared__ u16 SM[SMW];
    u16* a_lds = SM;
    u16* H = SM + 1024;
    int t = threadIdx.x, lane = t & 63, wave = t >> 6;
    int wm = wave >> 1, wn = wave & 1;
    int l15 = lane & 15, l4 = lane >> 4;
    int row0 = blockIdx.x * 32;
    int isf32 = dflag[0];

    f4v acc[8];
    b8v af, bfr[8];
    auto zacc = [&](){
        #pragma unroll
        for (int j = 0; j < 8; j++) acc[j] = {0.f,0.f,0.f,0.f};
    };
    auto rdW = [&](const u16* W, int kc){
        #pragma unroll
        for (int j = 0; j < 8; j++)
            bfr[j] = *(const b8v*)(W + (size_t)kc*8192 + ((wn*8 + j)*64 + lane)*8);
    };
    auto domf = [&](){
        #pragma unroll
        for (int j = 0; j < 8; j++)
            acc[j] = __builtin_amdgcn_mfma_f32_16x16x32_bf16(af, bfr[j], acc[j], 0, 0, 0);
    };
    auto layer = [&](const u16* Hin, const u16* Wg){
        zacc();
        for (int kc = 0; kc < 8; kc++){
            rdW(Wg, kc);
            int R = wm*16 + l15;
            int up = (kc*4 + l4) ^ (R & 31);
            af = *(const b8v*)&Hin[R*256 + up*8];
            domf();
        }
    };
    auto stLin = [&](u16* C){
        #pragma unroll
        for (int j = 0; j < 8; j++){
            int col = (wn*8 + j)*16 + l15;
            int rb = row0 + wm*16 + l4*4;
            #pragma unroll
            for (int r = 0; r < 4; r++)
                C[(size_t)(rb + r)*256 + col] = f2bf(acc[j][r]);
        }
    };

    // ---- PP GEMM: K=512 ----
    zacc();
    for (int kc = 0; kc < 16; kc++){
        uint4 ra;
        if (t < 128){
            int row = t >> 2, up = t & 3;
            int q = up ^ ((row >> 1) & 3);
            int rg = row0 + row;
            int kg = kc*32 + q*8;
            const u16* src = (kg < 256) ? penc + (size_t)rg*256 + kg
                                        : aggB + (size_t)rg*256 + (kg - 256);
            ra = *(const uint4*)src;
        }
        __syncthreads();
        if (t < 128) ((uint4*)a_lds)[t] = ra;
        __syncthreads();
        int R = wm*16 + l15;
        int up = l4 ^ ((R >> 1) & 3);
        af = *(const b8v*)&a_lds[R*32 + up*8];
        rdW(Wpp, kc);
        domf();
    }
    // ---- epilogue: bias + residual + relu -> H (LDS) [+ global peff] ----
    #pragma unroll
    for (int j = 0; j < 8; j++){
        int col = (wn*8 + j)*16 + l15;
        float bias = ldin(Bpp, col, isf32);
        int rb = wm*16 + l4*4;
        #pragma unroll
        for (int r = 0; r < 4; r++){
            int rr = rb + r;
            int row = row0 + rr;
            float v = acc[j][r] + bias + bf2f(res[(size_t)row*256 + col]);
            v = v > 0.f ? v : 0.f;
            int up = (col >> 3) ^ (rr & 31);
            H[rr*256 + up*8 + (col & 7)] = f2bf(v);
            if (MODE == 0) peff_out[(size_t)row*256 + col] = f2bf(v);
        }
    }
    __syncthreads();
    if (MODE == 0){
        layer(H, WrpB);                     stLin(Pr);
        layer(H, WrpB + (size_t)8*8192);    stLin(Ps);
    } else {
        u16* PH = SM + 1024 + 8192;               // 32 x 264
        float* sw1 = (float*)(SM + 1024 + 8192 + 8448);
        float* sb1 = (float*)(SM + 1024 + 8192 + 8448 + 1536);
        #pragma unroll
        for (int i = 0; i < 3; i++) sw1[t + i*256] = ldin(w1, t + i*256, isf32);
        if (t < 3) sb1[t] = ldin(b1, t, isf32);
        layer(H, Wpr0);
        #pragma unroll
        for (int j = 0; j < 8; j++){
            int col = (wn*8 + j)*16 + l15;
            float bias = ldin(Bpr0, col, isf32);
            int rb = wm*16 + l4*4;
            #pragma unroll
            for (int r = 0; r < 4; r++){
                float v = acc[j][r] + bias;
                PH[(rb + r)*264 + col] = f2bf(v > 0.f ? v : 0.f);
            }
        }
        __syncthreads();
        int row = t >> 3, dd = t & 7;
        if (dd < 3){
            int g = row0 + row;
            float s = sb1[dd] + s_cur[g*3 + dd];
            const u16* hr = &PH[row*264];
            #pragma unroll 8
            for (int k = 0; k < 256; k++)
                s += bf2f(hr[k]) * sw1[k*3 + dd];
            if (isf32) ((float*)out)[g*3 + dd] = s;
            else       ((u16*)out)[g*3 + dd]   = f2bf(s);
        }
    }
}

extern "C" void kernel_launch(void* const* d_in, const int* in_sizes, int n_in,
                              void* d_out, int out_size, void* d_ws, size_t ws_size,
                              hipStream_t stream) {
    const void* a_hist = d_in[0];
    const void* s_hist = d_in[1];
    const void* s_delta= d_in[2];
    const void* pe_w0 = d_in[3];  const void* pe_b0 = d_in[4];
    const void* pe_w1 = d_in[5];  const void* pe_b1 = d_in[6];
    const void* re_w0 = d_in[7];  const void* re_b0 = d_in[8];
    const void* re_w1 = d_in[9];  const void* re_b1 = d_in[10];
    const void* re_w2 = d_in[11]; const void* re_b2 = d_in[12];
    const void* rp_w  = d_in[13]; const void* rp_b  = d_in[14];
    const void* pp_w  = d_in[15]; const void* pp_b  = d_in[16];
    const void* pr_w0 = d_in[17]; const void* pr_b0 = d_in[18];
    const void* pr_w1 = d_in[19]; const void* pr_b1 = d_in[20];

    char* base = (char*)d_ws;
    size_t off = 0;
    auto alloc = [&](size_t bytes) -> char* {
        char* p = base + off;
        off += (bytes + 255) & ~(size_t)255;
        return p;
    };
    int*   dflag = (int*)  alloc(16);
    int*   ecount8 = (int*)alloc(64);
    float* s_cur = (float*)alloc(NPT*3*4);
    int*   cidx  = (int*)  alloc(NET*4);
    int*   csend = (int*)  alloc(NET*4);
    u16* pe_in = (u16*)alloc((size_t)NPT*32*2);
    u16* re_in = (u16*)alloc((size_t)NET*32*2);
    u16* penc  = (u16*)alloc((size_t)NPT*256*2);
    u16* aggB  = (u16*)alloc((size_t)NPT*256*2);
    u16* peffA = (u16*)alloc((size_t)NPT*256*2);
    u16* peffB = (u16*)alloc((size_t)NPT*256*2);
    u16* PrPs  = (u16*)alloc((size_t)2*NPT*256*2);
    u16* Erel  = (u16*)alloc((size_t)NET*256*2);
    u16* wsw   = (u16*)alloc((size_t)74*8192*2);

    u16* sw_pe0 = wsw + (size_t) 0*8192;
    u16* sw_pe1 = wsw + (size_t) 1*8192;
    u16* sw_re0 = wsw + (size_t) 9*8192;
    u16* sw_re1 = wsw + (size_t)10*8192;
    u16* sw_re2 = wsw + (size_t)18*8192;
    u16* sw_rp  = wsw + (size_t)26*8192;   // 0..7 rel | 8..15 recv | 16..23 send
    u16* sw_pp  = wsw + (size_t)50*8192;
    u16* sw_pr0 = wsw + (size_t)66*8192;

    u16* Pr = PrPs;
    u16* Ps = PrPs + (size_t)NPT*256;
    u16* sw_rpB = sw_rp + (size_t)8*8192;  // recv bank (send bank at +8 chunks more)

    hipMemsetAsync(ecount8, 0, 32, stream);

    k_setup<<<1090, 256, 0, stream>>>(a_hist, s_hist, s_delta,
        pe_w0, pe_w1, re_w0, re_w1, re_w2, rp_w, pp_w, pr_w0,
        wsw, dflag, s_cur, pe_in, ecount8, cidx, csend, re_in);

    k_edge<<<8*NRT + 125, 256, 0, stream>>>(re_in, pe_in,
        sw_re0, sw_re1, sw_re2, sw_rp, sw_pe0, sw_pe1, sw_rpB,
        re_b0, re_b1, re_b2, pe_b0, pe_b1, dflag, ecount8, Erel, penc, Pr, Ps);

    // step 1: agg + (PP + PrPs)
    k_rpagg<<<NPT, 256, 0, stream>>>(Erel, Pr, Ps, cidx, csend, rp_b, dflag, aggB);
    k_ppfuse2<0><<<125, 256, 0, stream>>>(penc, aggB, sw_pp, pp_b, penc, peffA,
        sw_rpB, Pr, Ps, nullptr, nullptr, nullptr, nullptr, nullptr, nullptr, dflag);
    // step 2
    k_rpagg<<<NPT, 256, 0, stream>>>(Erel, Pr, Ps, cidx, csend, rp_b, dflag, aggB);
    k_ppfuse2<0><<<125, 256, 0, stream>>>(penc, aggB, sw_pp, pp_b, peffA, peffB,
        sw_rpB, Pr, Ps, nullptr, nullptr, nullptr, nullptr, nullptr, nullptr, dflag);
    // step 3 + predictor + output
    k_rpagg<<<NPT, 256, 0, stream>>>(Erel, Pr, Ps, cidx, csend, rp_b, dflag, aggB);
    k_ppfuse2<1><<<125, 256, 0, stream>>>(penc, aggB, sw_pp, pp_b, peffB, nullptr,
        nullptr, nullptr, nullptr, sw_pr0, pr_b0, pr_w1, pr_b1, s_cur, (void*)d_out, dflag);
}

// Round 18
// 229.244 us; speedup vs baseline: 1.3074x; 1.2568x over previous
//
#include <hip/hip_runtime.h>
#include <hip/hip_bf16.h>

typedef unsigned short u16;
typedef unsigned int u32;

#define BATCH 4
#define NHIST 4
#define NPART 1000
#define NTOPK 10
#define NPT (BATCH*NPART)     // 4000 particles total
#define NET (NPT*NTOPK)       // 40000 edges capacity
#define EREG 5000             // per-region edge capacity (8 regions)
#define NRT 157               // relation tiles per region (ceil(EREG/32))

typedef __bf16 b8v __attribute__((ext_vector_type(8)));
typedef float  f4v __attribute__((ext_vector_type(4)));

__device__ __forceinline__ float bf2f(u16 b){
    return __uint_as_float(((u32)b) << 16);
}
__device__ __forceinline__ u16 f2bf(float f){
    u32 u = __float_as_uint(f);
    u32 r = u + 0x7FFF + ((u >> 16) & 1);  // RNE
    return (u16)(r >> 16);
}
__device__ __forceinline__ float ldin(const void* p, size_t i, int isf32){
    return isf32 ? ((const float*)p)[i] : bf2f(((const u16*)p)[i]);
}

// =============== setup: dtype-probe + weight swizzle + prep + topk+compact ===============
// grid 1090: blocks 0..73 weight swizzle, 74..89 prep, 90..1089 topk (wave = receiver).
__global__ __launch_bounds__(256) void k_setup(
    const void* __restrict__ a_hist, const void* __restrict__ s_hist,
    const void* __restrict__ s_delta,
    const void* w0, const void* w1, const void* w2, const void* w3,
    const void* w4, const void* w5, const void* w6, const void* w7,
    u16* __restrict__ wsw, int* __restrict__ dflag,
    float* __restrict__ s_cur, u16* __restrict__ pe_in,
    int* __restrict__ ecount8, int* __restrict__ cidx, int* __restrict__ csend,
    u16* __restrict__ re_in)
{
    __shared__ u32 SMEM[8192];
    __shared__ int sdet;
    __shared__ int wcnt[4], wbase[4];
    int t = threadIdx.x;
    if (t == 0) sdet = 0;
    __syncthreads();
    {
        const u16* p = (const u16*)a_hist;
        int bad = 0;
        for (int i = t; i < 2000; i += 256) bad |= (p[i] >> 15) & 1;
        if (bad) atomicOr(&sdet, 1);
    }
    __syncthreads();
    int isf32 = sdet;
    int bid = blockIdx.x;

    if (bid < 74){
        const int nck[8] = {1,8,1,8,8,24,16,8};
        const int Ks[8]  = {16,256,5,256,256,768,512,256};
        const void* srcs[8] = {w0,w1,w2,w3,w4,w5,w6,w7};
        int wi = 0, c = bid;
        while (c >= nck[wi]){ c -= nck[wi]; wi++; }
        const void* src = srcs[wi];
        int K = Ks[wi];
        u16* stage = (u16*)SMEM;
        #pragma unroll 4
        for (int kk = 0; kk < 32; kk++){
            int k = c*32 + kk;
            float v = (k < K) ? ldin(src, (size_t)k*256 + t, isf32) : 0.f;
            int e = (t >> 4)*512 + ((kk >> 3)*16 + (t & 15))*8 + (kk & 7);
            stage[e] = f2bf(v);
        }
        __syncthreads();
        uint4* dstv = (uint4*)(wsw + (size_t)bid * 8192);
        const uint4* sv = (const uint4*)stage;
        dstv[t] = sv[t];
        dstv[t + 256] = sv[t + 256];
        dstv[t + 512] = sv[t + 512];
        dstv[t + 768] = sv[t + 768];
        return;
    }
    if (bid < 90){
        if (bid == 74 && t == 0) dflag[0] = isf32;
        int g = (bid - 74)*256 + t;
        if (g >= NPT) return;
        int b = g / NPART, i = g - b*NPART;
        #pragma unroll
        for (int d = 0; d < 3; d++)
            s_cur[g*3 + d] = ldin(s_hist, (size_t)((b*NHIST + NHIST-1)*NPART + i)*3 + d, isf32);
        #pragma unroll
        for (int h = 0; h < NHIST; h++){
            #pragma unroll
            for (int d = 0; d < 3; d++)
                pe_in[g*32 + h*3 + d] = f2bf(ldin(s_delta, (size_t)((b*NHIST + h)*NPART + i)*3 + d, isf32));
            pe_in[g*32 + 12 + h] = f2bf(ldin(a_hist, (b*NHIST + h)*NPART + i, isf32));
        }
        #pragma unroll
        for (int k = 16; k < 32; k++) pe_in[g*32 + k] = 0;
        return;
    }
    // ---- topk: 1000 blocks, WAVE = RECEIVER (4/block) ----
    float* sx = (float*)SMEM;
    float* sy = sx + 1000;
    float* sz = sx + 2000;
    float* sa = sx + 3000;
    u32* raw  = SMEM + 4096;
    u32* rawa = SMEM + 4096 + 3072;
    int tb = bid - 90;
    int b = tb / 250, r0 = (tb % 250) * 4;
    int wid = t >> 6, lane = t & 63;
    {
        int sbase = (b*NHIST + NHIST-1)*NPART*3;
        int abase = (b*NHIST + NHIST-1)*NPART;
        if (isf32){
            const uint4* ps = (const uint4*)((const float*)s_hist + sbase);
            for (int i = t; i < 750; i += 256) ((uint4*)raw)[i] = ps[i];
            const uint4* pa = (const uint4*)((const float*)a_hist + abase);
            if (t < 250) ((uint4*)rawa)[t] = pa[t];
        } else {
            const uint4* ps = (const uint4*)((const u16*)s_hist + sbase);
            for (int i = t; i < 375; i += 256) ((uint4*)raw)[i] = ps[i];
            const uint4* pa = (const uint4*)((const u16*)a_hist + abase);
            if (t < 125) ((uint4*)rawa)[t] = pa[t];
        }
    }
    __syncthreads();
    for (int j = t; j < NPART; j += 256){
        float vx, vy, vz, va;
        if (isf32){
            vx = ((const float*)raw)[j*3+0]; vy = ((const float*)raw)[j*3+1];
            vz = ((const float*)raw)[j*3+2]; va = ((const float*)rawa)[j];
        } else {
            vx = bf2f(((const u16*)raw)[j*3+0]); vy = bf2f(((const u16*)raw)[j*3+1]);
            vz = bf2f(((const u16*)raw)[j*3+2]); va = bf2f(((const u16*)rawa)[j]);
        }
        sx[j] = vx; sy[j] = vy; sz[j] = vz; sa[j] = va;
    }
    __syncthreads();
    int i = r0 + wid;
    float xi = sx[i], yi = sy[i], zi = sz[i];
    float ai = sa[i];
    bool tool_i = ai > 0.5f;
    float thr = tool_i ? -1.0f : 0.25f;

    float bd[NTOPK]; int bj[NTOPK];
    #pragma unroll
    for (int k = 0; k < NTOPK; k++){ bd[k] = 3.0e38f; bj[k] = 1 << 30; }
    for (int j = lane; j < NPART; j += 64){
        float dx = xi - sx[j], dy = yi - sy[j], dz = zi - sz[j];
        float d = dx*dx + dy*dy + dz*dz;
        if (d < thr && d < bd[NTOPK-1]){
            float v = d; int vj = j;
            #pragma unroll
            for (int k = 0; k < NTOPK; k++){
                bool sw = v < bd[k];
                float tv = bd[k]; int tj = bj[k];
                if (sw){ bd[k] = v; bj[k] = vj; v = tv; vj = tj; }
            }
        }
    }
    float myd = 3.0e38f; int myj = 0;
    #pragma unroll
    for (int r = 0; r < NTOPK; r++){
        float v = bd[0]; int vj = bj[0];
        #pragma unroll
        for (int s = 32; s > 0; s >>= 1){
            float ov = __shfl_xor(v, s);
            int   oj = __shfl_xor(vj, s);
            if (ov < v || (ov == v && oj < vj)){ v = ov; vj = oj; }
        }
        if (lane == r){ myd = v; myj = vj; }
        bool owner = (bd[0] == v) && (bj[0] == vj);
        if (owner){
            #pragma unroll
            for (int k = 0; k < NTOPK-1; k++){ bd[k] = bd[k+1]; bj[k] = bj[k+1]; }
            bd[NTOPK-1] = 3.0e38f; bj[NTOPK-1] = 1 << 30;
        }
    }
    bool fl = (lane < NTOPK) && (myd < 0.25f);
    int cnt = __popcll(__ballot(fl));
    if (lane == 0) wcnt[wid] = cnt;
    __syncthreads();
    if (t == 0){
        int c0 = wcnt[0], c1 = wcnt[1], c2 = wcnt[2], c3 = wcnt[3];
        int reg = tb & 7;
        int bb = atomicAdd(&ecount8[reg], c0 + c1 + c2 + c3) + reg*EREG;
        wbase[0] = bb; wbase[1] = bb + c0; wbase[2] = bb + c0 + c1; wbase[3] = bb + c0 + c1 + c2;
    }
    __syncthreads();
    int base = wbase[wid];
    if (lane < NTOPK){
        int gp = b*NPART + i;
        int ce = fl ? base + lane : -1;
        cidx[gp*NTOPK + lane] = ce;
        if (ce >= 0){
            int j = myj;
            csend[ce] = b*NPART + j;
            u32 q0 = (u32)f2bf(ai)        | ((u32)f2bf(sa[j])      << 16);
            u32 q1 = (u32)f2bf(xi - sx[j]) | ((u32)f2bf(yi - sy[j]) << 16);
            u32 q2 = (u32)f2bf(zi - sz[j]);
            uint4 v0 = {q0, q1, q2, 0};
            uint4 zz = {0, 0, 0, 0};
            uint4* rp = (uint4*)(re_in + (size_t)ce*32);
            rp[0] = v0; rp[1] = zz; rp[2] = zz; rp[3] = zz;
        }
    }
}

// =============== fused edge chain + particle encoder (+ Pr0/Ps0), W double-buffered ===============
__global__ __launch_bounds__(256) void k_edge(
    const u16* __restrict__ re_in, const u16* __restrict__ pe_in,
    const u16* __restrict__ W0, const u16* __restrict__ W1,
    const u16* __restrict__ W2, const u16* __restrict__ W3,
    const u16* __restrict__ PW0, const u16* __restrict__ PW1,
    const u16* __restrict__ WrpB,
    const void* __restrict__ B0, const void* __restrict__ B1,
    const void* __restrict__ B2,
    const void* __restrict__ PB0, const void* __restrict__ PB1,
    const int* __restrict__ dflag, const int* __restrict__ ecount8,
    u16* __restrict__ Eout, u16* __restrict__ penc,
    u16* __restrict__ Pr, u16* __restrict__ Ps)
{
    __shared__ u16 H1[32*256];
    __shared__ u16 H2[32*256];
    __shared__ u16 S[32*32];
    int t = threadIdx.x, lane = t & 63, wave = t >> 6;
    int wm = wave >> 1, wn = wave & 1;
    int isf32 = dflag[0];
    int l15 = lane & 15, l4 = lane >> 4;

    f4v acc[8];
    b8v af, bfA[8], bfB[8];
    auto zacc = [&](){
        #pragma unroll
        for (int j = 0; j < 8; j++) acc[j] = {0.f,0.f,0.f,0.f};
    };
    auto rdWto = [&](b8v* dst, const u16* W, int kc){
        #pragma unroll
        for (int j = 0; j < 8; j++)
            dst[j] = *(const b8v*)(W + (size_t)kc*8192 + ((wn*8 + j)*64 + lane)*8);
    };
    auto domf = [&](b8v* wf){
        #pragma unroll
        for (int j = 0; j < 8; j++)
            acc[j] = __builtin_amdgcn_mfma_f32_16x16x32_bf16(af, wf[j], acc[j], 0, 0, 0);
    };
    auto rdA = [&](const u16* Hin, int kc){
        int R = wm*16 + l15;
        int up = (kc*4 + l4) ^ (R & 31);
        af = *(const b8v*)&Hin[R*256 + up*8];
    };
    // W double-buffered layer: prefetch kc+1 while MFMAing kc
    auto layer = [&](const u16* Hin, const u16* Wg){
        zacc();
        rdWto(bfA, Wg, 0);
        #pragma unroll
        for (int kc = 0; kc < 8; kc += 2){
            rdWto(bfB, Wg, kc + 1);
            rdA(Hin, kc); domf(bfA);
            if (kc + 2 < 8) rdWto(bfA, Wg, kc + 2);
            rdA(Hin, kc + 1); domf(bfB);
        }
    };
    auto epiLDS = [&](u16* Hout, const void* Wb){
        #pragma unroll
        for (int j = 0; j < 8; j++){
            int col = (wn*8 + j)*16 + l15;
            float bias = ldin(Wb, col, isf32);
            int rb = wm*16 + l4*4;
            #pragma unroll
            for (int r = 0; r < 4; r++){
                float v = acc[j][r] + bias;
                v = v > 0.f ? v : 0.f;
                int rr = rb + r;
                int up = (col >> 3) ^ (rr & 31);
                Hout[rr*256 + up*8 + (col & 7)] = f2bf(v);
            }
        }
    };
    auto stLin = [&](u16* C, int row0){
        #pragma unroll
        for (int j = 0; j < 8; j++){
            int col = (wn*8 + j)*16 + l15;
            int rb = row0 + wm*16 + l4*4;
            #pragma unroll
            for (int r = 0; r < 4; r++)
                C[(size_t)(rb + r)*256 + col] = f2bf(acc[j][r]);
        }
    };

    if (blockIdx.x >= 8*NRT){
        // ---------- particle encoder + Pr0/Ps0 ----------
        int row0 = (blockIdx.x - 8*NRT) * 32;
        if (t < 128){
            int row = t >> 2, q = t & 3;
            int rg = row0 + row;
            uint4 v = *(const uint4*)(pe_in + (size_t)rg*32 + q*8);
            int up = q ^ (row & 3);
            *(uint4*)&S[row*32 + up*8] = v;
        }
        __syncthreads();
        zacc();
        {
            rdWto(bfA, PW0, 0);
            int R = wm*16 + l15;
            int up = l4 ^ (R & 3);
            af = *(const b8v*)&S[R*32 + up*8];
            domf(bfA);
        }
        epiLDS(H1, PB0);
        __syncthreads();
        layer(H1, PW1);
        #pragma unroll
        for (int j = 0; j < 8; j++){
            int col = (wn*8 + j)*16 + l15;
            float bias = ldin(PB1, col, isf32);
            int rb = wm*16 + l4*4;
            #pragma unroll
            for (int r = 0; r < 4; r++){
                int rr = rb + r;
                float v = acc[j][r] + bias;
                v = v > 0.f ? v : 0.f;
                penc[(size_t)(row0 + rr)*256 + col] = f2bf(v);
                int up = (col >> 3) ^ (rr & 31);
                H2[rr*256 + up*8 + (col & 7)] = f2bf(v);
            }
        }
        __syncthreads();
        layer(H2, WrpB);                      stLin(Pr, row0);
        layer(H2, WrpB + (size_t)8*8192);     stLin(Ps, row0);
        return;
    }

    // ---------- relation chain on 8-region compacted edges (32-row tiles) ----------
    int region = blockIdx.x / NRT;
    int local  = blockIdx.x - region*NRT;
    int ec = ecount8[region];
    if (local*32 >= ec) return;
    int row0 = region*EREG + local*32;
    if (t < 128){
        int row = t >> 2, q = t & 3;
        int rg = row0 + row; if (rg >= NET) rg = NET - 1;
        uint4 v = *(const uint4*)(re_in + (size_t)rg*32 + q*8);
        int up = q ^ (row & 3);
        *(uint4*)&S[row*32 + up*8] = v;
    }
    __syncthreads();

    zacc();
    {
        rdWto(bfA, W0, 0);
        int R = wm*16 + l15;
        int up = l4 ^ (R & 3);
        af = *(const b8v*)&S[R*32 + up*8];
        domf(bfA);
    }
    epiLDS(H1, B0);
    __syncthreads();
    layer(H1, W1); epiLDS(H2, B1);
    __syncthreads();
    layer(H2, W2); epiLDS(H1, B2);
    __syncthreads();
    layer(H1, W3);
    stLin(Eout, row0);
}

// =============== edge assembly + relu + aggregation over COMPACTED edges ===============
__global__ void k_rpagg(const u16* __restrict__ Erel, const u16* __restrict__ Pr,
                        const u16* __restrict__ Ps,
                        const int* __restrict__ cidx, const int* __restrict__ csend,
                        const void* __restrict__ rp_b,
                        const int* __restrict__ dflag, u16* __restrict__ agg)
{
    int g = blockIdx.x, c = threadIdx.x;
    int isf32 = dflag[0];
    float bias = ldin(rp_b, c, isf32);
    float pr = bf2f(Pr[(size_t)g*256 + c]);
    float s = 0.f;
    #pragma unroll
    for (int k = 0; k < NTOPK; k++){
        int ce = cidx[g*NTOPK + k];
        if (ce >= 0){
            float v = bf2f(Erel[(size_t)ce*256 + c]) + pr
                    + bf2f(Ps[(size_t)csend[ce]*256 + c]) + bias;
            s += v > 0.f ? v : 0.f;
        }
    }
    agg[(size_t)g*256 + c] = f2bf(s);
}

// =============== fused PP GEMM + {PrPs | predictor}: 16-row tiles, 250 blocks ===============
// Wave wn handles coltiles wn*4..wn*4+3. PP: K=512 concat [penc|aggB] + bias + res + relu.
// MODE 0: Pr/Ps = peff @ rp_w{recv,send} from the LDS tile. MODE 1: predictor + out.
template<int MODE>
__global__ __launch_bounds__(256) void k_ppfuse2(
    const u16* __restrict__ penc, const u16* __restrict__ aggB,
    const u16* __restrict__ Wpp, const void* __restrict__ Bpp,
    const u16* __restrict__ res, u16* __restrict__ peff_out,
    const u16* __restrict__ WrpB, u16* __restrict__ Pr, u16* __restrict__ Ps,
    const u16* __restrict__ Wpr0, const void* __restrict__ Bpr0,
    const void* __restrict__ w1, const void* __restrict__ b1,
    const float* __restrict__ s_cur, void* __restrict__ out,
    const int* __restrict__ dflag)
{
    constexpr int SMW = (MODE == 1) ? (512 + 4096 + 4224 + 1536 + 8) : (512 + 4096);
    __shared__ u16 SM[SMW];
    u16* a_lds = SM;            // 16 x 32
    u16* H = SM + 512;          // 16 x 256
    int t = threadIdx.x, lane = t & 63, wn = t >> 6;
    int l15 = lane & 15, l4 = lane >> 4;
    int row0 = blockIdx.x * 16;
    int isf32 = dflag[0];

    f4v acc[4];
    b8v af, bfA[4], bfB[4];
    auto zacc = [&](){
        #pragma unroll
        for (int j = 0; j < 4; j++) acc[j] = {0.f,0.f,0.f,0.f};
    };
    auto rdWto = [&](b8v* dst, const u16* W, int kc){
        #pragma unroll
        for (int j = 0; j < 4; j++)
            dst[j] = *(const b8v*)(W + (size_t)kc*8192 + ((wn*4 + j)*64 + lane)*8);
    };
    auto domf = [&](b8v* wf){
        #pragma unroll
        for (int j = 0; j < 4; j++)
            acc[j] = __builtin_amdgcn_mfma_f32_16x16x32_bf16(af, wf[j], acc[j], 0, 0, 0);
    };
    auto rdH = [&](int kc){
        int R = l15;
        int up = (kc*4 + l4) ^ R;       // R < 16
        af = *(const b8v*)&H[R*256 + up*8];
    };
    auto layer = [&](const u16* Wg){
        zacc();
        rdWto(bfA, Wg, 0);
        #pragma unroll
        for (int kc = 0; kc < 8; kc += 2){
            rdWto(bfB, Wg, kc + 1);
            rdH(kc); domf(bfA);
            if (kc + 2 < 8) rdWto(bfA, Wg, kc + 2);
            rdH(kc + 1); domf(bfB);
        }
    };
    auto stLin = [&](u16* C){
        #pragma unroll
        for (int j = 0; j < 4; j++){
            int col = (wn*4 + j)*16 + l15;
            int rb = row0 + l4*4;
            #pragma unroll
            for (int r = 0; r < 4; r++)
                C[(size_t)(rb + r)*256 + col] = f2bf(acc[j][r]);
        }
    };
    auto stageA = [&](int kc){
        uint4 ra;
        if (t < 64){
            int row = t >> 2, up = t & 3;
            int q = up ^ ((row >> 1) & 3);
            int rg = row0 + row;
            int kg = kc*32 + q*8;
            const u16* src = (kg < 256) ? penc + (size_t)rg*256 + kg
                                        : aggB + (size_t)rg*256 + (kg - 256);
            ra = *(const uint4*)src;
        }
        __syncthreads();
        if (t < 64) ((uint4*)a_lds)[t] = ra;
        __syncthreads();
        int R = l15;
        int up = l4 ^ ((R >> 1) & 3);
        af = *(const b8v*)&a_lds[R*32 + up*8];
    };

    // ---- PP GEMM: K=512, W double-buffered ----
    zacc();
    rdWto(bfA, Wpp, 0);
    for (int kc = 0; kc < 16; kc += 2){
        stageA(kc);
        rdWto(bfB, Wpp, kc + 1);
        domf(bfA);
        stageA(kc + 1);
        if (kc + 2 < 16) rdWto(bfA, Wpp, kc + 2);
        domf(bfB);
    }
    // ---- epilogue: bias + residual + relu -> H (LDS) [+ global peff] ----
    #pragma unroll
    for (int j = 0; j < 4; j++){
        int col = (wn*4 + j)*16 + l15;
        float bias = ldin(Bpp, col, isf32);
        int rb = l4*4;
        #pragma unroll
        for (int r = 0; r < 4; r++){
            int rr = rb + r;
            int row = row0 + rr;
            float v = acc[j][r] + bias + bf2f(res[(size_t)row*256 + col]);
            v = v > 0.f ? v : 0.f;
            int up = (col >> 3) ^ rr;
            H[rr*256 + up*8 + (col & 7)] = f2bf(v);
            if (MODE == 0) peff_out[(size_t)row*256 + col] = f2bf(v);
        }
    }
    __syncthreads();
    if (MODE == 0){
        layer(WrpB);                     stLin(Pr);
        layer(WrpB + (size_t)8*8192);    stLin(Ps);
    } else {
        u16* PH = SM + 512 + 4096;            // 16 x 264
        float* sw1 = (float*)(SM + 512 + 4096 + 4224);
        float* sb1 = (float*)(SM + 512 + 4096 + 4224 + 1536);
        #pragma unroll
        for (int i = 0; i < 3; i++) sw1[t + i*256] = ldin(w1, t + i*256, isf32);
        if (t < 3) sb1[t] = ldin(b1, t, isf32);
        layer(Wpr0);
        #pragma unroll
        for (int j = 0; j < 4; j++){
            int col = (wn*4 + j)*16 + l15;
            float bias = ldin(Bpr0, col, isf32);
            int rb = l4*4;
            #pragma unroll
            for (int r = 0; r < 4; r++){
                float v = acc[j][r] + bias;
                PH[(rb + r)*264 + col] = f2bf(v > 0.f ? v : 0.f);
            }
        }
        __syncthreads();
        int row = t >> 3, dd = t & 7;
        if (t < 128 && dd < 3){
            int g = row0 + row;
            float s = sb1[dd] + s_cur[g*3 + dd];
            const u16* hr = &PH[row*264];
            #pragma unroll 8
            for (int k = 0; k < 256; k++)
                s += bf2f(hr[k]) * sw1[k*3 + dd];
            if (isf32) ((float*)out)[g*3 + dd] = s;
            else       ((u16*)out)[g*3 + dd]   = f2bf(s);
        }
    }
}

extern "C" void kernel_launch(void* const* d_in, const int* in_sizes, int n_in,
                              void* d_out, int out_size, void* d_ws, size_t ws_size,
                              hipStream_t stream) {
    const void* a_hist = d_in[0];
    const void* s_hist = d_in[1];
    const void* s_delta= d_in[2];
    const void* pe_w0 = d_in[3];  const void* pe_b0 = d_in[4];
    const void* pe_w1 = d_in[5];  const void* pe_b1 = d_in[6];
    const void* re_w0 = d_in[7];  const void* re_b0 = d_in[8];
    const void* re_w1 = d_in[9];  const void* re_b1 = d_in[10];
    const void* re_w2 = d_in[11]; const void* re_b2 = d_in[12];
    const void* rp_w  = d_in[13]; const void* rp_b  = d_in[14];
    const void* pp_w  = d_in[15]; const void* pp_b  = d_in[16];
    const void* pr_w0 = d_in[17]; const void* pr_b0 = d_in[18];
    const void* pr_w1 = d_in[19]; const void* pr_b1 = d_in[20];

    char* base = (char*)d_ws;
    size_t off = 0;
    auto alloc = [&](size_t bytes) -> char* {
        char* p = base + off;
        off += (bytes + 255) & ~(size_t)255;
        return p;
    };
    int*   dflag = (int*)  alloc(16);
    int*   ecount8 = (int*)alloc(64);
    float* s_cur = (float*)alloc(NPT*3*4);
    int*   cidx  = (int*)  alloc(NET*4);
    int*   csend = (int*)  alloc(NET*4);
    u16* pe_in = (u16*)alloc((size_t)NPT*32*2);
    u16* re_in = (u16*)alloc((size_t)NET*32*2);
    u16* penc  = (u16*)alloc((size_t)NPT*256*2);
    u16* aggB  = (u16*)alloc((size_t)NPT*256*2);
    u16* peffA = (u16*)alloc((size_t)NPT*256*2);
    u16* peffB = (u16*)alloc((size_t)NPT*256*2);
    u16* PrPs  = (u16*)alloc((size_t)2*NPT*256*2);
    u16* Erel  = (u16*)alloc((size_t)NET*256*2);
    u16* wsw   = (u16*)alloc((size_t)74*8192*2);

    u16* sw_pe0 = wsw + (size_t) 0*8192;
    u16* sw_pe1 = wsw + (size_t) 1*8192;
    u16* sw_re0 = wsw + (size_t) 9*8192;
    u16* sw_re1 = wsw + (size_t)10*8192;
    u16* sw_re2 = wsw + (size_t)18*8192;
    u16* sw_rp  = wsw + (size_t)26*8192;   // 0..7 rel | 8..15 recv | 16..23 send
    u16* sw_pp  = wsw + (size_t)50*8192;
    u16* sw_pr0 = wsw + (size_t)66*8192;

    u16* Pr = PrPs;
    u16* Ps = PrPs + (size_t)NPT*256;
    u16* sw_rpB = sw_rp + (size_t)8*8192;  // recv bank (send bank at +8 chunks more)

    hipMemsetAsync(ecount8, 0, 32, stream);

    k_setup<<<1090, 256, 0, stream>>>(a_hist, s_hist, s_delta,
        pe_w0, pe_w1, re_w0, re_w1, re_w2, rp_w, pp_w, pr_w0,
        wsw, dflag, s_cur, pe_in, ecount8, cidx, csend, re_in);

    k_edge<<<8*NRT + 125, 256, 0, stream>>>(re_in, pe_in,
        sw_re0, sw_re1, sw_re2, sw_rp, sw_pe0, sw_pe1, sw_rpB,
        re_b0, re_b1, re_b2, pe_b0, pe_b1, dflag, ecount8, Erel, penc, Pr, Ps);

    // step 1: agg + (PP + PrPs)
    k_rpagg<<<NPT, 256, 0, stream>>>(Erel, Pr, Ps, cidx, csend, rp_b, dflag, aggB);
    k_ppfuse2<0><<<250, 256, 0, stream>>>(penc, aggB, sw_pp, pp_b, penc, peffA,
        sw_rpB, Pr, Ps, nullptr, nullptr, nullptr, nullptr, nullptr, nullptr, dflag);
    // step 2
    k_rpagg<<<NPT, 256, 0, stream>>>(Erel, Pr, Ps, cidx, csend, rp_b, dflag, aggB);
    k_ppfuse2<0><<<250, 256, 0, stream>>>(penc, aggB, sw_pp, pp_b, peffA, peffB,
        sw_rpB, Pr, Ps, nullptr, nullptr, nullptr, nullptr, nullptr, nullptr, dflag);
    // step 3 + predictor + output
    k_rpagg<<<NPT, 256, 0, stream>>>(Erel, Pr, Ps, cidx, csend, rp_b, dflag, aggB);
    k_ppfuse2<1><<<250, 256, 0, stream>>>(penc, aggB, sw_pp, pp_b, peffB, nullptr,
        nullptr, nullptr, nullptr, sw_pr0, pr_b0, pr_w1, pr_b1, s_cur, (void*)d_out, dflag);
}